// Round 4
// baseline (593.996 us; speedup 1.0000x reference)
//
#include <hip/hip_runtime.h>
#include <hip/hip_bf16.h>
#include <cstdint>
#include <cstddef>

// WideLSTM: N=32 blocks, I=64, H=128, B=16, T=256.
// 128 WGs = 32 blocks x 4 batch-groups, 1024 thr = 16 waves = 4 waves/SIMD.
// GATE-INTERLEAVED A-TILES (R3): each 16-row A-tile = 4h x 4gates, row
// r=4*dh+j (weight row g=128*j+h); lane's f32x4 acc = all 4 gate pre-acts
// for one (h,b).  No cross-wave exchange, ONE lgkm-only barrier/step.
// R4 CHANGE: xbuf LDS path removed entirely.  Each lane loads its own x
// B-fragment floats DIRECTLY from global (4 x dwordx4 = 64B), issued 2 steps
// ahead into a register double-buffer (xsA/xsB), converted to bf16 frags at
// the top of the consuming step (packed cvt fills the LDS-stall bubble).
// Loop LDS = 4 h ds_read_b128 + 1 h ds_write_b16 per wave — the minimum the
// MFMA B-layout permits.  Model: per-CU LDS pipe is additive with MFMA pipe
// (R2/R3 fit: step ~= 12*LDSops + 930 + const), so -32 reads ~= -384 cyc.

#define TSTEPS 256

typedef float  f32x4  __attribute__((ext_vector_type(4)));
typedef float  f32x2  __attribute__((ext_vector_type(2)));
typedef __bf16 bf16x8 __attribute__((ext_vector_type(8)));
typedef short  s16x8  __attribute__((ext_vector_type(8)));

union Frag { s16x8 s; bf16x8 b; };

#define KSIG -1.4426950408889634f   // -1/ln2 (sigmoid)
#define KTAN  2.8853900817779268f   //  2/ln2 (tanh)

__device__ __forceinline__ short f2bf(float f) {
  uint32_t u = __builtin_bit_cast(uint32_t, f);
  u += 0x7fffu + ((u >> 16) & 1u);
  return (short)(u >> 16);
}

// lgkm-only barrier: global loads/stores stay in flight across it
__device__ __forceinline__ void sync_lds() {
  asm volatile("s_waitcnt lgkmcnt(0)" ::: "memory");
  __builtin_amdgcn_s_barrier();
  asm volatile("" ::: "memory");
}

__device__ __forceinline__ float sig2(float z) {   // rcp(1 + exp2(z))
  return __builtin_amdgcn_rcpf(1.f + __builtin_amdgcn_exp2f(z));
}

__device__ __forceinline__ f32x4 mf(const Frag a, const Frag bb, f32x4 c) {
  return __builtin_amdgcn_mfma_f32_16x16x32_bf16(a.b, bb.b, c, 0, 0, 0);
}

__global__ __launch_bounds__(1024, 4) void wide_lstm(
    const float* __restrict__ x,   const float* __restrict__ h0,
    const float* __restrict__ c0,  const float* __restrict__ wih,
    const float* __restrict__ whh, const float* __restrict__ bih,
    const float* __restrict__ bhh, float* __restrict__ out)
{
  const int n     = blockIdx.x & 31;
  const int bg    = blockIdx.x >> 5;     // batch group: batches [4bg, 4bg+4)
  const int tid   = threadIdx.x;
  const int wv    = tid >> 6;            // wave 0..15: h-range [8wv, 8wv+8)
  const int lane  = tid & 63;
  const int col   = lane & 15;
  const int quad  = lane >> 4;
  const int b4    = col & 3;             // batch within group
  const int e2    = col >> 2;            // dup index 0..3
  const int tsel  = e2 >> 1;             // tile this lane's epilogue owns
  const int hbase = 8 * wv;
  const int hl    = hbase + quad + 4 * tsel;  // this lane's h (0..127)
  const int b     = 4 * bg + b4;         // global batch this lane updates
  const bool wr   = ((e2 & 1) == 0);     // writer lane (one per (h,b))

  // h only: 4 rows x stride 144 shorts (bank-tuned, <=2-way, measured 0 conf)
  __shared__ alignas(16) short hbuf[2][4 * 144];

  // ---- weights -> persistent A-fragments, gate-interleaved rows ----
  // tile T row r=col: dh=col>>2, j=col&3; g = 128*(col&3) + hbase + 4T + (col>>2)
  Frag wfr[6][2];
#pragma unroll
  for (int T = 0; T < 2; ++T) {
    const int g = 128 * (col & 3) + hbase + 4 * T + (col >> 2);
#pragma unroll
    for (int s = 0; s < 6; ++s) {
      const int k0 = 32 * s + quad * 8;
      const float* p = (s < 2) ? (wih + (size_t)(n * 512 + g) * 64  + k0)
                               : (whh + (size_t)(n * 512 + g) * 128 + (k0 - 64));
      const f32x4 lo = *(const f32x4*)p;
      const f32x4 hi = *(const f32x4*)(p + 4);
      Frag f;
      f.s[0]=f2bf(lo[0]); f.s[1]=f2bf(lo[1]); f.s[2]=f2bf(lo[2]); f.s[3]=f2bf(lo[3]);
      f.s[4]=f2bf(hi[0]); f.s[5]=f2bf(hi[1]); f.s[6]=f2bf(hi[2]); f.s[7]=f2bf(hi[3]);
      wfr[s][T] = f;
    }
  }

  // ---- bias in acc layout: cb[T][r] = bias[g = 128*r + hbase + 4T + quad] ----
  f32x4 cb[2];
#pragma unroll
  for (int T = 0; T < 2; ++T) {
#pragma unroll
    for (int r = 0; r < 4; ++r) {
      const int g = n * 512 + 128 * r + hbase + 4 * T + quad;
      cb[T][r] = bih[g] + bhh[g];
    }
  }

  // ---- init h(0) ----
  if (tid < 256) {
    const int bi = tid >> 6, j2 = (tid & 63) * 2;
    const f32x2 hv = *(const f32x2*)(h0 + (size_t)(4 * bg + bi) * 4096 + n * 128 + j2);
    *(uint32_t*)&hbuf[0][bi * 144 + j2] =
        (uint32_t)(uint16_t)f2bf(hv[0]) | ((uint32_t)(uint16_t)f2bf(hv[1]) << 16);
  }
  float cg = c0[(size_t)b * 4096 + n * 128 + hl];

  // ---- per-lane x source: this lane's B-frag floats for batch b ----
  // frag needs x[k = 32s' + 8*quad + jj], s'=0,1 -> float offsets 0..7 from
  // 8*quad and 32+8*quad: dwordx4 at +0, +4, +32, +36.
  const float* xlane = x + (size_t)b * (TSTEPS * 2048) + n * 64 + 8 * quad;

  // ---- register x double-buffer: xsB <- x(1) (consumed at S=0 top) ----
  f32x4 xsA0, xsA1, xsA2, xsA3, xsB0, xsB1, xsB2, xsB3;
  {
    const float* p = xlane + 2048;
    xsB0 = *(const f32x4*)p;        xsB1 = *(const f32x4*)(p + 4);
    xsB2 = *(const f32x4*)(p + 32); xsB3 = *(const f32x4*)(p + 36);
  }

  // ---- acpre(0) = bias + Wih*x(0), x(0) fragged direct from global ----
  f32x4 acpre[2];
  {
    const f32x4 a0 = *(const f32x4*)xlane;
    const f32x4 a1 = *(const f32x4*)(xlane + 4);
    const f32x4 a2 = *(const f32x4*)(xlane + 32);
    const f32x4 a3 = *(const f32x4*)(xlane + 36);
    Frag xf0, xf1;
#pragma unroll
    for (int r = 0; r < 4; ++r) {
      xf0.b[r]     = (__bf16)a0[r];
      xf0.b[4 + r] = (__bf16)a1[r];
      xf1.b[r]     = (__bf16)a2[r];
      xf1.b[4 + r] = (__bf16)a3[r];
    }
#pragma unroll
    for (int T = 0; T < 2; ++T)
      acpre[T] = mf(wfr[1][T], xf1, mf(wfr[0][T], xf0, cb[T]));
  }
  __syncthreads();   // h(0) staged

  const int hoff  = b4 * 144 + quad * 8;     // h B-frag base
  const int hwoff = b4 * 144 + hl;           // h write slot (writer lanes)
  float* outp = out + (size_t)b * (TSTEPS * 4096) + n * 128 + hl;
  float ho = 0.f;
  const f32x4 kzero = (f32x4){0.f, 0.f, 0.f, 0.f};

  // Step S (CUR=S&1): top: issue x(S+2) loads into XC (vmcnt slack = 1 full
  // step); convert XN = x(S+1) (arrived during S-1) -> bf16 frags; read h(S)
  // frags.  In-window: 8 Whh MFMAs (two 2-deep chains/tile from acpre).
  // Tail: 4 Wih MFMAs -> acpre(S+1).  Epilogue on lane's tsel tile.
  // ONE lgkm-only barrier at step end (global loads/stores stay in flight).
#define LSTM_STEP(CUR, NXT, S, XC0, XC1, XC2, XC3, XN0, XN1, XN2, XN3)       \
  {                                                                          \
    {                                                                        \
      const int tt = ((S) + 2 < TSTEPS) ? (S) + 2 : (TSTEPS - 1);            \
      const float* p = xlane + (size_t)tt * 2048;                            \
      XC0 = *(const f32x4*)p;        XC1 = *(const f32x4*)(p + 4);           \
      XC2 = *(const f32x4*)(p + 32); XC3 = *(const f32x4*)(p + 36);          \
    }                                                                        \
    Frag xg0, xg1;                                                           \
    _Pragma("unroll") for (int r = 0; r < 4; ++r) {                          \
      xg0.b[r]     = (__bf16)XN0[r];                                         \
      xg0.b[4 + r] = (__bf16)XN1[r];                                         \
      xg1.b[r]     = (__bf16)XN2[r];                                         \
      xg1.b[4 + r] = (__bf16)XN3[r];                                         \
    }                                                                        \
    Frag hf0, hf1, hf2, hf3;                                                 \
    hf0.s = *(const s16x8*)&hbuf[CUR][hoff];                                 \
    hf1.s = *(const s16x8*)&hbuf[CUR][hoff + 32];                            \
    hf2.s = *(const s16x8*)&hbuf[CUR][hoff + 64];                            \
    hf3.s = *(const s16x8*)&hbuf[CUR][hoff + 96];                            \
    f32x4 ac1[2], ac2[2];                                                    \
    _Pragma("unroll") for (int T = 0; T < 2; ++T) {                          \
      ac1[T] = mf(wfr[3][T], hf1, mf(wfr[2][T], hf0, acpre[T]));             \
      ac2[T] = mf(wfr[5][T], hf3, mf(wfr[4][T], hf2, kzero));                \
    }                                                                        \
    _Pragma("unroll") for (int T = 0; T < 2; ++T)                            \
      acpre[T] = mf(wfr[1][T], xg1, mf(wfr[0][T], xg0, cb[T]));              \
    const f32x4 ps = tsel ? (ac1[1] + ac2[1]) : (ac1[0] + ac2[0]);           \
    const float si = sig2(KSIG * ps[0]);                                     \
    const float sf = sig2(KSIG * ps[1]);                                     \
    const float sg = sig2(KTAN * ps[2]);                                     \
    const float so = sig2(KSIG * ps[3]);                                     \
    float cn = __builtin_fmaf(sf, cg, si);                                   \
    cn = __builtin_fmaf(-2.f, si * sg, cn);                                  \
    cg = cn;                                                                 \
    ho = so * __builtin_fmaf(-2.f, sig2(KTAN * cn), 1.f);                    \
    if (wr) {                                                                \
      hbuf[NXT][hwoff] = f2bf(ho);                                           \
      *outp = ho;                                                            \
    }                                                                        \
    outp += 4096;                                                            \
    sync_lds();                                                              \
  }

  for (int t = 0; t < TSTEPS; t += 2) {
    LSTM_STEP(0, 1, t,     xsA0, xsA1, xsA2, xsA3, xsB0, xsB1, xsB2, xsB3);
    LSTM_STEP(1, 0, t + 1, xsB0, xsB1, xsB2, xsB3, xsA0, xsA1, xsA2, xsA3);
  }
#undef LSTM_STEP

  // ---- h_n / c_n (writer lanes) ----
  if (wr) {
    out[16777216 +         (size_t)b * 4096 + n * 128 + hl] = ho;
    out[16777216 + 65536 + (size_t)b * 4096 + n * 128 + hl] = cg;
  }
}

extern "C" void kernel_launch(void* const* d_in, const int* in_sizes, int n_in,
                              void* d_out, int out_size, void* d_ws, size_t ws_size,
                              hipStream_t stream) {
  const float* x   = (const float*)d_in[0];
  const float* h0  = (const float*)d_in[1];
  const float* c0  = (const float*)d_in[2];
  const float* wih = (const float*)d_in[3];
  const float* whh = (const float*)d_in[4];
  const float* bih = (const float*)d_in[5];
  const float* bhh = (const float*)d_in[6];
  float* out = (float*)d_out;
  wide_lstm<<<128, 1024, 0, stream>>>(x, h0, c0, wih, whh, bih, bhh, out);
}

// Round 5
// 283.347 us; speedup vs baseline: 2.0964x; 2.0964x over previous
//
#include <hip/hip_runtime.h>
#include <hip/hip_bf16.h>
#include <cstdint>
#include <cstddef>

// WideLSTM: N=32 blocks, I=64, H=128, B=16, T=256.
// 128 WGs = 32 blocks x 4 batch-groups, 1024 thr = 16 waves = 4 waves/SIMD.
// R2 K-split pair structure, rebalanced:
//   wave w (0..7):   Whh slices s2,s3 (k[0,64)), 2-deep chain from bias cb.
//   wave w+8:        Whh slices s4,s5 (k[64,128)), 2-deep chain from carried
//                    x-partial acpre_p; plus (in its post-exchange dead
//                    window) the 8 Wih MFMAs computing acpre_p(S+1).
// Partner pre-selects its lane's element (e2) and ships ONE f32x4/lane via
// pbuf; w adds and runs the epilogue.  In-window MFMA/SIMD: 930 -> 620 cyc;
// the 310 cyc of x-MFMAs run under w's transcendental epilogue.
// s_setprio(1) wraps in-window MFMA clusters (wave role-split exists).
// 2 lgkm-only barriers/step (B: partials ready, A': bufs ready).
// x flows ONLY through LDS (R4 lesson: per-lane global B-frags are toxic).

#define TSTEPS 256

typedef float  f32x4  __attribute__((ext_vector_type(4)));
typedef float  f32x2  __attribute__((ext_vector_type(2)));
typedef __bf16 bf16x8 __attribute__((ext_vector_type(8)));
typedef short  s16x8  __attribute__((ext_vector_type(8)));

union Frag { s16x8 s; bf16x8 b; };

#define KSIG -1.4426950408889634f   // -1/ln2 (sigmoid)
#define KTAN  2.8853900817779268f   //  2/ln2 (tanh)

__device__ __forceinline__ short f2bf(float f) {
  uint32_t u = __builtin_bit_cast(uint32_t, f);
  u += 0x7fffu + ((u >> 16) & 1u);
  return (short)(u >> 16);
}

// lgkm-only barrier: global loads/stores stay in flight across it
__device__ __forceinline__ void sync_lds() {
  asm volatile("s_waitcnt lgkmcnt(0)" ::: "memory");
  __builtin_amdgcn_s_barrier();
  asm volatile("" ::: "memory");
}

__device__ __forceinline__ float sig2(float z) {   // rcp(1 + exp2(z))
  return __builtin_amdgcn_rcpf(1.f + __builtin_amdgcn_exp2f(z));
}

__device__ __forceinline__ f32x4 mf(const Frag a, const Frag bb, f32x4 c) {
  return __builtin_amdgcn_mfma_f32_16x16x32_bf16(a.b, bb.b, c, 0, 0, 0);
}

__device__ __forceinline__ float sel4(const f32x4 a, bool m1, bool m2) {
  const float u01 = m1 ? a[1] : a[0];
  const float u23 = m1 ? a[3] : a[2];
  return m2 ? u23 : u01;
}

__global__ __launch_bounds__(1024, 4) void wide_lstm(
    const float* __restrict__ x,   const float* __restrict__ h0,
    const float* __restrict__ c0,  const float* __restrict__ wih,
    const float* __restrict__ whh, const float* __restrict__ bih,
    const float* __restrict__ bhh, float* __restrict__ out)
{
  const int n    = blockIdx.x & 31;
  const int bg   = blockIdx.x >> 5;      // batch group: batches [4bg, 4bg+4)
  const int tid  = threadIdx.x;
  const int wv   = tid >> 6;             // wave 0..15
  const int w    = wv & 7;               // pair id / h-tile [16w, 16w+16)
  const bool isw = (wv < 8);             // front half: epilogue owner
  const int lane = tid & 63;
  const int col  = lane & 15;
  const int quad = lane >> 4;
  const int b4   = col & 3;              // batch within group
  const int e2   = col >> 2;             // acc row r this lane keeps (0..3)
  const int hloc = 4 * quad + e2;
  const int hgl  = 16 * w + hloc;        // h within block (0..127)
  const int b    = 4 * bg + b4;          // global batch this lane updates

  // h: 4 rows x stride 144 shorts (bank-tuned); x: 4 rows x stride 96
  __shared__ alignas(16) short hbuf[2][4 * 144];
  __shared__ alignas(16) short xbuf[2][4 * 96];
  // pair-exchange partials: one f32x4 per partner lane, contiguous b128
  __shared__ alignas(16) float pbuf[8][64][4];

  // ---- weights -> persistent A-fragments ----
  // w: slices {s2,s3} (wfr[0..1]); partner: {s4,s5,s0,s1} (wfr[0..3])
  Frag wfr[4][4];
#pragma unroll
  for (int j = 0; j < 4; ++j) {
    const int g = 128 * j + 16 * w + col;
    const int nsl = isw ? 2 : 4;
    for (int sl = 0; sl < nsl; ++sl) {
      const int s = isw ? (sl + 2) : (sl < 2 ? sl + 4 : sl - 2);
      const int k0 = 32 * s + quad * 8;
      const float* p = (s < 2) ? (wih + (size_t)(n * 512 + g) * 64  + k0)
                               : (whh + (size_t)(n * 512 + g) * 128 + (k0 - 64));
      const f32x4 lo = *(const f32x4*)p;
      const f32x4 hi = *(const f32x4*)(p + 4);
      Frag f;
      f.s[0]=f2bf(lo[0]); f.s[1]=f2bf(lo[1]); f.s[2]=f2bf(lo[2]); f.s[3]=f2bf(lo[3]);
      f.s[4]=f2bf(hi[0]); f.s[5]=f2bf(hi[1]); f.s[6]=f2bf(hi[2]); f.s[7]=f2bf(hi[3]);
      wfr[sl][j] = f;
    }
  }

  const int hoff  = b4 * 144 + quad * 8;     // h B-frag base
  const int hwoff = b4 * 144 + hgl;          // h write slot
  const int xoff  = b4 * 96  + quad * 8;     // x B-frag base
  const bool m1 = (e2 & 1), m2 = (e2 & 2);
  const f32x4 kzero = (f32x4){0.f, 0.f, 0.f, 0.f};

  f32x4 cb[4], acpre[4];
  float cg = 0.f, ho = 0.f;
  float* outp = nullptr;
  float xr = 0.f;
  const float* xnext = nullptr;

  if (isw) {
    // ---- bias in MFMA C-layout ----
#pragma unroll
    for (int j = 0; j < 4; ++j) {
      const int base = n * 512 + 128 * j + 16 * w + quad * 4;
      const f32x4 b1 = *(const f32x4*)(bih + base);
      const f32x4 b2 = *(const f32x4*)(bhh + base);
#pragma unroll
      for (int r = 0; r < 4; ++r) cb[j][r] = b1[r] + b2[r];
    }
    // ---- init h(0) ----
    if (tid < 256) {
      const int bi = tid >> 6, j2 = (tid & 63) * 2;
      const f32x2 hv = *(const f32x2*)(h0 + (size_t)(4 * bg + bi) * 4096 + n * 128 + j2);
      *(uint32_t*)&hbuf[0][bi * 144 + j2] =
          (uint32_t)(uint16_t)f2bf(hv[0]) | ((uint32_t)(uint16_t)f2bf(hv[1]) << 16);
    }
    cg = c0[(size_t)b * 4096 + n * 128 + hgl];
    outp = out + (size_t)b * (TSTEPS * 4096) + n * 128 + hgl;
  } else {
    // ---- x staging init (waves 8-11): x(1)->xbuf[1]; xr=x(2); cursor x(3) ----
    if (tid < 768) {
      const int bq = (tid >> 6) & 3;
      const int kq = tid & 63;
      const float* xp = x + (size_t)(4 * bg + bq) * (TSTEPS * 2048) + n * 64 + kq;
      xbuf[1][bq * 96 + kq] = f2bf(xp[2048]);
      xr = xp[2 * 2048];
      xnext = xp + 3 * 2048;
    }
    // ---- acpre_p(0) = Wih*x(0), x(0) fragged direct from global (one-time) ----
    {
      const float* q = x + (size_t)b * (TSTEPS * 2048) + n * 64 + 8 * quad;
      const f32x4 a0 = *(const f32x4*)q;
      const f32x4 a1 = *(const f32x4*)(q + 4);
      const f32x4 a2 = *(const f32x4*)(q + 32);
      const f32x4 a3 = *(const f32x4*)(q + 36);
      Frag xf0, xf1;
#pragma unroll
      for (int r = 0; r < 4; ++r) {
        xf0.s[r]     = f2bf(a0[r]);
        xf0.s[4 + r] = f2bf(a1[r]);
        xf1.s[r]     = f2bf(a2[r]);
        xf1.s[4 + r] = f2bf(a3[r]);
      }
#pragma unroll
      for (int j = 0; j < 4; ++j)
        acpre[j] = mf(wfr[3][j], xf1, mf(wfr[2][j], xf0, kzero));
    }
  }
  __syncthreads();   // barrier A of step 0

  if (isw) {
    // ================= epilogue-owner wave loop =================
    // [top] ds_read hf0,hf1 -> 8 MFMA (s2,s3 from cb) -> sel
    // [B] + partner f32x4 -> trans epilogue -> write h(NXT), out  [A']
#define WSTEP(CUR, NXT, S)                                                   \
  {                                                                          \
    Frag hf0, hf1;                                                           \
    hf0.s = *(const s16x8*)&hbuf[CUR][hoff];                                 \
    hf1.s = *(const s16x8*)&hbuf[CUR][hoff + 32];                            \
    f32x4 ac1[4];                                                            \
    __builtin_amdgcn_s_setprio(1);                                           \
    _Pragma("unroll") for (int j = 0; j < 4; ++j)                            \
      ac1[j] = mf(wfr[0][j], hf0, cb[j]);                                    \
    _Pragma("unroll") for (int j = 0; j < 4; ++j)                            \
      ac1[j] = mf(wfr[1][j], hf1, ac1[j]);                                   \
    __builtin_amdgcn_s_setprio(0);                                           \
    float pre[4];                                                            \
    _Pragma("unroll") for (int j = 0; j < 4; ++j)                            \
      pre[j] = sel4(ac1[j], m1, m2);                                         \
    sync_lds(); /* B: partner partials ready */                              \
    const f32x4 vv = *(const f32x4*)&pbuf[w][lane][0];                       \
    pre[0] += vv[0]; pre[1] += vv[1]; pre[2] += vv[2]; pre[3] += vv[3];      \
    const float si = sig2(KSIG * pre[0]);                                    \
    const float sf = sig2(KSIG * pre[1]);                                    \
    const float sg = sig2(KTAN * pre[2]);                                    \
    const float so = sig2(KSIG * pre[3]);                                    \
    float cn = __builtin_fmaf(sf, cg, si);                                   \
    cn = __builtin_fmaf(-2.f, si * sg, cn);                                  \
    cg = cn;                                                                 \
    ho = so * __builtin_fmaf(-2.f, sig2(KTAN * cn), 1.f);                    \
    hbuf[NXT][hwoff] = f2bf(ho);                                             \
    *outp = ho;                                                              \
    outp += 4096;                                                            \
    sync_lds(); /* A' */                                                     \
  }
    for (int t = 0; t < TSTEPS; t += 2) {
      WSTEP(0, 1, t);
      WSTEP(1, 0, t + 1);
    }
#undef WSTEP
    // ---- h_n / c_n (one float per w lane) ----
    out[16777216 +         (size_t)b * 4096 + n * 128 + hgl] = ho;
    out[16777216 + 65536 + (size_t)b * 4096 + n * 128 + hgl] = cg;
  } else {
    // ================= partner wave loop =================
    // [top] ds_read hf2,hf3, stage x(S+2), 8 MFMA (s4,s5 from acpre_p),
    // sel -> pbuf  [B]  xg reads (x(S+1)) -> 8 Wih MFMA -> acpre_p(S+1)
    // (runs under w's epilogue)  [A']
    const int sxoff = ((tid >> 6) & 3) * 96 + (tid & 63);
    const bool stg = (tid < 768);
#define VSTEP(CUR, NXT, S)                                                   \
  {                                                                          \
    Frag hf2, hf3;                                                           \
    hf2.s = *(const s16x8*)&hbuf[CUR][hoff + 64];                            \
    hf3.s = *(const s16x8*)&hbuf[CUR][hoff + 96];                            \
    if (stg) {                                                               \
      xbuf[CUR][sxoff] = f2bf(xr);                                           \
      if ((S) + 3 < TSTEPS) { xr = *xnext; xnext += 2048; }                  \
    }                                                                        \
    f32x4 ac[4];                                                             \
    __builtin_amdgcn_s_setprio(1);                                           \
    _Pragma("unroll") for (int j = 0; j < 4; ++j)                            \
      ac[j] = mf(wfr[0][j], hf2, acpre[j]);                                  \
    _Pragma("unroll") for (int j = 0; j < 4; ++j)                            \
      ac[j] = mf(wfr[1][j], hf3, ac[j]);                                     \
    __builtin_amdgcn_s_setprio(0);                                           \
    f32x4 vv;                                                                \
    vv[0] = sel4(ac[0], m1, m2);                                             \
    vv[1] = sel4(ac[1], m1, m2);                                             \
    vv[2] = sel4(ac[2], m1, m2);                                             \
    vv[3] = sel4(ac[3], m1, m2);                                             \
    *(f32x4*)&pbuf[w][lane][0] = vv;                                         \
    sync_lds(); /* B */                                                      \
    Frag xg0, xg1;                                                           \
    xg0.s = *(const s16x8*)&xbuf[NXT][xoff];                                 \
    xg1.s = *(const s16x8*)&xbuf[NXT][xoff + 32];                            \
    _Pragma("unroll") for (int j = 0; j < 4; ++j)                            \
      acpre[j] = mf(wfr[2][j], xg0, kzero);                                  \
    _Pragma("unroll") for (int j = 0; j < 4; ++j)                            \
      acpre[j] = mf(wfr[3][j], xg1, acpre[j]);                               \
    sync_lds(); /* A' */                                                     \
  }
    for (int t = 0; t < TSTEPS; t += 2) {
      VSTEP(0, 1, t);
      VSTEP(1, 0, t + 1);
    }
#undef VSTEP
  }
}

extern "C" void kernel_launch(void* const* d_in, const int* in_sizes, int n_in,
                              void* d_out, int out_size, void* d_ws, size_t ws_size,
                              hipStream_t stream) {
  const float* x   = (const float*)d_in[0];
  const float* h0  = (const float*)d_in[1];
  const float* c0  = (const float*)d_in[2];
  const float* wih = (const float*)d_in[3];
  const float* whh = (const float*)d_in[4];
  const float* bih = (const float*)d_in[5];
  const float* bhh = (const float*)d_in[6];
  float* out = (float*)d_out;
  wide_lstm<<<128, 1024, 0, stream>>>(x, h0, c0, wih, whh, bih, bhh, out);
}

// Round 6
// 281.723 us; speedup vs baseline: 2.1084x; 1.0058x over previous
//
#include <hip/hip_runtime.h>
#include <hip/hip_bf16.h>
#include <cstdint>
#include <cstddef>

// WideLSTM: N=32 blocks, I=64, H=128, B=16, T=256.
// 128 WGs = 32 blocks x 4 batch-groups, 768 thr = 12 waves = 3 waves/SIMD.
// SINGLE-BARRIER 3-ROLE STRUCTURE:
//  - compute waves 0..7: full Whh K per tile (16 MFMAs, two 2-deep chains
//    from bias cb), epilogue, h/out writes.  h-tile [16w,16w+16).
//  - helper waves 8..11 (one per SIMD): next step's x-projection partials
//    for TWO compute tiles (16 MFMAs from xbuf frags), PRE-SELECTED to one
//    f32x4 per lane, written to pbuf[(S+1)&1]; plus all x staging.
// x-partials cross on the EXISTING end-of-step barrier (x(S+1) known at S),
// so there is NO mid-step barrier: ONE lgkm-only barrier per step.
// LDS/step/CU: 48 b128 reads (8x(4 hf + 1 pbuf) + 4x2 xg) ~ R1-level.
// MFMA/SIMD/step: 2x16 + 16 = 48 = 930 cyc floor (conserved).
// All cross-wave edges (hbuf/xbuf/pbuf, double-buffered) separated by
// exactly one barrier.  No setprio (R5 evidence).  c register-resident.

#define TSTEPS 256

typedef float  f32x4  __attribute__((ext_vector_type(4)));
typedef float  f32x2  __attribute__((ext_vector_type(2)));
typedef __bf16 bf16x8 __attribute__((ext_vector_type(8)));
typedef short  s16x8  __attribute__((ext_vector_type(8)));

union Frag { s16x8 s; bf16x8 b; };

#define KSIG -1.4426950408889634f   // -1/ln2 (sigmoid)
#define KTAN  2.8853900817779268f   //  2/ln2 (tanh)

__device__ __forceinline__ short f2bf(float f) {
  uint32_t u = __builtin_bit_cast(uint32_t, f);
  u += 0x7fffu + ((u >> 16) & 1u);
  return (short)(u >> 16);
}

// lgkm-only barrier: global loads/stores stay in flight across it
__device__ __forceinline__ void sync_lds() {
  asm volatile("s_waitcnt lgkmcnt(0)" ::: "memory");
  __builtin_amdgcn_s_barrier();
  asm volatile("" ::: "memory");
}

__device__ __forceinline__ float sig2(float z) {   // rcp(1 + exp2(z))
  return __builtin_amdgcn_rcpf(1.f + __builtin_amdgcn_exp2f(z));
}

__device__ __forceinline__ f32x4 mf(const Frag a, const Frag bb, f32x4 c) {
  return __builtin_amdgcn_mfma_f32_16x16x32_bf16(a.b, bb.b, c, 0, 0, 0);
}

__device__ __forceinline__ float sel4(const f32x4 a, bool m1, bool m2) {
  const float u01 = m1 ? a[1] : a[0];
  const float u23 = m1 ? a[3] : a[2];
  return m2 ? u23 : u01;
}

__global__ __launch_bounds__(768, 2) void wide_lstm(
    const float* __restrict__ x,   const float* __restrict__ h0,
    const float* __restrict__ c0,  const float* __restrict__ wih,
    const float* __restrict__ whh, const float* __restrict__ bih,
    const float* __restrict__ bhh, float* __restrict__ out)
{
  const int n    = blockIdx.x & 31;
  const int bg   = blockIdx.x >> 5;      // batch group: batches [4bg, 4bg+4)
  const int tid  = threadIdx.x;
  const int wv   = tid >> 6;             // wave 0..11
  const bool isw = (wv < 8);             // compute role
  const int w    = wv & 7;               // compute: h-tile [16w,16w+16)
  const int hw   = wv - 8;               // helper id 0..3 (serves w=2hw,2hw+1)
  const int lane = tid & 63;
  const int col  = lane & 15;
  const int quad = lane >> 4;
  const int b4   = col & 3;              // batch within group
  const int e2   = col >> 2;             // acc row r this lane keeps (0..3)
  const int hloc = 4 * quad + e2;
  const int hgl  = 16 * w + hloc;        // h within block (0..127)
  const int b    = 4 * bg + b4;          // global batch this lane updates

  // h: 4 rows x stride 144 shorts (bank-tuned); x: 4 rows x stride 96
  __shared__ alignas(16) short hbuf[2][4 * 144];
  __shared__ alignas(16) short xbuf[2][4 * 96];
  // x-partials: [parity][compute wave][lane] f32x4 (pre-selected, j-indexed)
  __shared__ alignas(16) float pbuf[2][8][64][4];

  const int hoff  = b4 * 144 + quad * 8;     // h B-frag base
  const int hwoff = b4 * 144 + hgl;          // h write slot
  const int xoff  = b4 * 96  + quad * 8;     // x B-frag base
  const bool m1 = (e2 & 1), m2 = (e2 & 2);
  const f32x4 kzero = (f32x4){0.f, 0.f, 0.f, 0.f};

  if (isw) {
    // ================= COMPUTE WAVES =================
    // weights: full Whh K: wfr[sl][j], sl=0..3 <-> k[32sl, 32sl+32)
    Frag wfr[4][4];
#pragma unroll
    for (int j = 0; j < 4; ++j) {
      const int g = 128 * j + 16 * w + col;
#pragma unroll
      for (int sl = 0; sl < 4; ++sl) {
        const float* p = whh + (size_t)(n * 512 + g) * 128 + 32 * sl + quad * 8;
        const f32x4 lo = *(const f32x4*)p;
        const f32x4 hi = *(const f32x4*)(p + 4);
        Frag f;
        f.s[0]=f2bf(lo[0]); f.s[1]=f2bf(lo[1]); f.s[2]=f2bf(lo[2]); f.s[3]=f2bf(lo[3]);
        f.s[4]=f2bf(hi[0]); f.s[5]=f2bf(hi[1]); f.s[6]=f2bf(hi[2]); f.s[7]=f2bf(hi[3]);
        wfr[sl][j] = f;
      }
    }
    // bias (both) in MFMA C-layout
    f32x4 cb[4];
#pragma unroll
    for (int j = 0; j < 4; ++j) {
      const int base = n * 512 + 128 * j + 16 * w + quad * 4;
      const f32x4 b1 = *(const f32x4*)(bih + base);
      const f32x4 b2 = *(const f32x4*)(bhh + base);
#pragma unroll
      for (int r = 0; r < 4; ++r) cb[j][r] = b1[r] + b2[r];
    }
    // init h(0)
    if (tid < 256) {
      const int bi = tid >> 6, j2 = (tid & 63) * 2;
      const f32x2 hv = *(const f32x2*)(h0 + (size_t)(4 * bg + bi) * 4096 + n * 128 + j2);
      *(uint32_t*)&hbuf[0][bi * 144 + j2] =
          (uint32_t)(uint16_t)f2bf(hv[0]) | ((uint32_t)(uint16_t)f2bf(hv[1]) << 16);
    }
    float cg = c0[(size_t)b * 4096 + n * 128 + hgl];
    float* outp = out + (size_t)b * (TSTEPS * 4096) + n * 128 + hgl;
    float ho = 0.f;
    __syncthreads();   // h(0), pbuf[0], xbuf[1] staged

    // Step S (P=S&1): read h(S) from hbuf[P], xpart(S) from pbuf[P]
    // -> 16 Whh MFMAs (two 2-deep chains) -> pre = sel+sel+xpart -> trans
    // -> write h(S+1) to hbuf[Q], out.  ONE lgkm barrier.
#define CSTEP(P, Q, S)                                                       \
  {                                                                          \
    Frag hf0, hf1, hf2, hf3;                                                 \
    hf0.s = *(const s16x8*)&hbuf[P][hoff];                                   \
    hf1.s = *(const s16x8*)&hbuf[P][hoff + 32];                              \
    hf2.s = *(const s16x8*)&hbuf[P][hoff + 64];                              \
    hf3.s = *(const s16x8*)&hbuf[P][hoff + 96];                              \
    const f32x4 xp4 = *(const f32x4*)&pbuf[P][w][lane][0];                   \
    f32x4 ac1[4], ac2[4];                                                    \
    _Pragma("unroll") for (int j = 0; j < 4; ++j) {                          \
      ac1[j] = mf(wfr[0][j], hf0, cb[j]);                                    \
      ac2[j] = mf(wfr[2][j], hf2, kzero);                                    \
    }                                                                        \
    _Pragma("unroll") for (int j = 0; j < 4; ++j) {                          \
      ac1[j] = mf(wfr[1][j], hf1, ac1[j]);                                   \
      ac2[j] = mf(wfr[3][j], hf3, ac2[j]);                                   \
    }                                                                        \
    float pre[4];                                                            \
    _Pragma("unroll") for (int j = 0; j < 4; ++j)                            \
      pre[j] = sel4(ac1[j], m1, m2) + sel4(ac2[j], m1, m2) + xp4[j];         \
    const float si = sig2(KSIG * pre[0]);                                    \
    const float sf = sig2(KSIG * pre[1]);                                    \
    const float sg = sig2(KTAN * pre[2]);                                    \
    const float so = sig2(KSIG * pre[3]);                                    \
    float cn = __builtin_fmaf(sf, cg, si);                                   \
    cn = __builtin_fmaf(-2.f, si * sg, cn);                                  \
    cg = cn;                                                                 \
    ho = so * __builtin_fmaf(-2.f, sig2(KTAN * cn), 1.f);                    \
    hbuf[Q][hwoff] = f2bf(ho);                                               \
    *outp = ho;                                                              \
    outp += 4096;                                                            \
    sync_lds();                                                              \
  }
    for (int t = 0; t < TSTEPS; t += 2) {
      CSTEP(0, 1, t);
      CSTEP(1, 0, t + 1);
    }
#undef CSTEP
    // h_n / c_n (one float per lane; all (h,b) unique across wave)
    out[16777216 +         (size_t)b * 4096 + n * 128 + hgl] = ho;
    out[16777216 + 65536 + (size_t)b * 4096 + n * 128 + hgl] = cg;

  } else {
    // ================= HELPER WAVES =================
    // weights: Wih for two served tiles: wfx[T2][s][j]
    Frag wfx[2][2][4];
#pragma unroll
    for (int T2 = 0; T2 < 2; ++T2) {
      const int wt = 2 * hw + T2;
#pragma unroll
      for (int j = 0; j < 4; ++j) {
        const int g = 128 * j + 16 * wt + col;
#pragma unroll
        for (int s = 0; s < 2; ++s) {
          const float* p = wih + (size_t)(n * 512 + g) * 64 + 32 * s + quad * 8;
          const f32x4 lo = *(const f32x4*)p;
          const f32x4 hi = *(const f32x4*)(p + 4);
          Frag f;
          f.s[0]=f2bf(lo[0]); f.s[1]=f2bf(lo[1]); f.s[2]=f2bf(lo[2]); f.s[3]=f2bf(lo[3]);
          f.s[4]=f2bf(hi[0]); f.s[5]=f2bf(hi[1]); f.s[6]=f2bf(hi[2]); f.s[7]=f2bf(hi[3]);
          wfx[T2][s][j] = f;
        }
      }
    }
    // x staging init: wave hw stages batch hw.  xbuf[1] <- x(1); xr = x(2).
    const int sxoff = hw * 96 + lane;
    const float* xp = x + (size_t)(4 * bg + hw) * (TSTEPS * 2048) + n * 64 + lane;
    xbuf[1][sxoff] = f2bf(xp[2048]);
    float xr = xp[2 * 2048];
    const float* xnext = xp + 3 * 2048;
    // xpart(0) from x(0), fragged direct from global (one-time)
    {
      const float* q = x + (size_t)b * (TSTEPS * 2048) + n * 64 + 8 * quad;
      const f32x4 a0 = *(const f32x4*)q;
      const f32x4 a1 = *(const f32x4*)(q + 4);
      const f32x4 a2 = *(const f32x4*)(q + 32);
      const f32x4 a3 = *(const f32x4*)(q + 36);
      Frag xf0, xf1;
#pragma unroll
      for (int r = 0; r < 4; ++r) {
        xf0.s[r]     = f2bf(a0[r]);
        xf0.s[4 + r] = f2bf(a1[r]);
        xf1.s[r]     = f2bf(a2[r]);
        xf1.s[4 + r] = f2bf(a3[r]);
      }
#pragma unroll
      for (int T2 = 0; T2 < 2; ++T2) {
        f32x4 acc[4];
#pragma unroll
        for (int j = 0; j < 4; ++j)
          acc[j] = mf(wfx[T2][1][j], xf1, mf(wfx[T2][0][j], xf0, kzero));
        f32x4 vv;
        vv[0] = sel4(acc[0], m1, m2); vv[1] = sel4(acc[1], m1, m2);
        vv[2] = sel4(acc[2], m1, m2); vv[3] = sel4(acc[3], m1, m2);
        *(f32x4*)&pbuf[0][2 * hw + T2][lane][0] = vv;
      }
    }
    __syncthreads();

    // Step S (P=S&1, Q=(S+1)&1): read xg = x(S+1) from xbuf[Q] (staged @S-1);
    // stage x(S+2) -> xbuf[P]; 16 Wih MFMAs -> sel -> pbuf[Q] (xpart(S+1)).
#define HSTEP(P, Q, S)                                                       \
  {                                                                          \
    Frag xg0, xg1;                                                           \
    xg0.s = *(const s16x8*)&xbuf[Q][xoff];                                   \
    xg1.s = *(const s16x8*)&xbuf[Q][xoff + 32];                              \
    xbuf[P][sxoff] = f2bf(xr);                                               \
    if ((S) + 3 < TSTEPS) { xr = *xnext; xnext += 2048; }                    \
    _Pragma("unroll") for (int T2 = 0; T2 < 2; ++T2) {                       \
      f32x4 acc[4];                                                          \
      _Pragma("unroll") for (int j = 0; j < 4; ++j)                          \
        acc[j] = mf(wfx[T2][0][j], xg0, kzero);                              \
      _Pragma("unroll") for (int j = 0; j < 4; ++j)                          \
        acc[j] = mf(wfx[T2][1][j], xg1, acc[j]);                             \
      f32x4 vv;                                                              \
      vv[0] = sel4(acc[0], m1, m2); vv[1] = sel4(acc[1], m1, m2);            \
      vv[2] = sel4(acc[2], m1, m2); vv[3] = sel4(acc[3], m1, m2);            \
      *(f32x4*)&pbuf[Q][2 * hw + T2][lane][0] = vv;                          \
    }                                                                        \
    sync_lds();                                                              \
  }
    for (int t = 0; t < TSTEPS; t += 2) {
      HSTEP(0, 1, t);
      HSTEP(1, 0, t + 1);
    }
#undef HSTEP
  }
}

extern "C" void kernel_launch(void* const* d_in, const int* in_sizes, int n_in,
                              void* d_out, int out_size, void* d_ws, size_t ws_size,
                              hipStream_t stream) {
  const float* x   = (const float*)d_in[0];
  const float* h0  = (const float*)d_in[1];
  const float* c0  = (const float*)d_in[2];
  const float* wih = (const float*)d_in[3];
  const float* whh = (const float*)d_in[4];
  const float* bih = (const float*)d_in[5];
  const float* bhh = (const float*)d_in[6];
  float* out = (float*)d_out;
  wide_lstm<<<128, 768, 0, stream>>>(x, h0, c0, wih, whh, bih, bhh, out);
}